// Round 6
// baseline (57.202 us; speedup 1.0000x reference)
//
#include <hip/hip_runtime.h>
#include <hip/hip_bf16.h>
#include <hip/hip_cooperative_groups.h>

namespace cg = cooperative_groups;

#define NS   256
#define DIN  512
#define DHID 1024

typedef __attribute__((ext_vector_type(8)))  short bf16x8;
typedef __attribute__((ext_vector_type(4)))  float f32x4;
typedef __attribute__((ext_vector_type(16))) float f32x16;

static __device__ __forceinline__ short f2bf(float f) {
    return __builtin_bit_cast(short, __float2bfloat16(f));   // RNE
}

static __device__ __forceinline__ bf16x8 cvt8(f32x4 a, f32x4 b) {
    bf16x8 r;
    r[0] = f2bf(a[0]); r[1] = f2bf(a[1]); r[2] = f2bf(a[2]); r[3] = f2bf(a[3]);
    r[4] = f2bf(b[0]); r[5] = f2bf(b[1]); r[6] = f2bf(b[2]); r[7] = f2bf(b[3]);
    return r;
}

// Single cooperative kernel, 256 blocks x 256 threads, grid.sync() between phases.
//
// Phase 1 (feat): Z = [x1;x2] @ W1 + b1; Hb = relu(Z), Gb = (Z>0)*w2 (bf16, ws).
//   Block = 32 rows x 64 cols; 4 waves = 2 col-tiles x 2-way K-split (16 ksteps
//   each), 32x32x16 MFMA, LDS pair-reduce, epilogue by waves 0/1.
//   W1 B-frags read directly from f32 (strided scalar; coalesced across the
//   32-lane col group; same total instruction count as r5's K1).
// Phase 2 (gram): out[i,j] = (x1_i.x2_j + 1)*(g1_i.g2_j) + h1_i.h2_j + 1.
//   Block = one 16x16 tile; 4 waves K-split c (16 ksteps), g,h (32 ksteps each);
//   LDS reduce; wave 0 combines + writes.
//
// Frag layouts (verified m74/m101/m89): 32x32 A/B lane l -> row/col=l&31,
// k=(l>>5)*8+i; D: col=l&31, row=(r&3)+8*(r>>2)+4*(l>>5). 16x16 A/B lane l ->
// row/col=l&15, k=(l>>4)*8+i; D: col=l&15, row=(l>>4)*4+r.
__global__ __launch_bounds__(256) void ntk_coop(
    const float* __restrict__ x1, const float* __restrict__ x2,
    const float* __restrict__ W1, const float* __restrict__ b1,
    const float* __restrict__ w2,
    short* __restrict__ Hb, short* __restrict__ Gb,
    float* __restrict__ out)
{
    const int tid = threadIdx.x;
    const int l   = tid & 63;
    const int w   = tid >> 6;
    const int b   = blockIdx.x;

    __shared__ __align__(16) char smem[16384];
    auto red1 = reinterpret_cast<f32x16(*)[2][64]>(smem);  // [ct][ks][lane]
    auto red2 = reinterpret_cast<f32x4(*)[4][64]>(smem);   // [mat][wave][lane]

    // ---------------- phase 1: features ----------------
    {
        const int lc = l & 31;          // A-row / B-col / D-col
        const int hk = l >> 5;          // k half-group
        const int ct = w >> 1;          // col-tile 0/1
        const int ks = w & 1;           // k-split half
        const int m0 = (b >> 4) * 32;
        const int n0 = (b & 15) * 64;
        const int col = n0 + ct * 32 + lc;

        const float* X  = (m0 < NS) ? (x1 + (size_t)m0 * DIN)
                                    : (x2 + (size_t)(m0 - NS) * DIN);
        const float* ap = X + lc * DIN + hk * 8;
        const float* bp = W1 + (size_t)(hk * 8) * DHID + col;

        f32x16 acc = {};
        #pragma unroll 4
        for (int t = ks * 16; t < ks * 16 + 16; ++t) {
            const int k0 = t * 16;
            bf16x8 a = cvt8(*(const f32x4*)(ap + k0), *(const f32x4*)(ap + k0 + 4));
            f32x4 b0v, b1v;
            #pragma unroll
            for (int i = 0; i < 4; ++i) b0v[i] = bp[(size_t)(k0 + i) * DHID];
            #pragma unroll
            for (int i = 0; i < 4; ++i) b1v[i] = bp[(size_t)(k0 + 4 + i) * DHID];
            acc = __builtin_amdgcn_mfma_f32_32x32x16_bf16(a, cvt8(b0v, b1v), acc, 0, 0, 0);
        }
        red1[ct][ks][l] = acc;
        __syncthreads();
        if (w < 2) {
            f32x16 s = red1[w][0][l] + red1[w][1][l];
            const int colw = n0 + w * 32 + lc;
            const float bbv = b1[colw], wwv = w2[colw];
            #pragma unroll
            for (int r = 0; r < 16; ++r) {
                const int row = m0 + (r & 3) + 8 * (r >> 2) + 4 * hk;
                float z = s[r] + bbv;
                Hb[row * DHID + colw] = f2bf(z > 0.f ? z   : 0.f);
                Gb[row * DHID + colw] = f2bf(z > 0.f ? wwv : 0.f);
            }
        }
    }

    // ---------------- grid-wide barrier ----------------
    cg::this_grid().sync();

    // ---------------- phase 2: grams + combine ----------------
    {
        const int lr = l & 15;
        const int kg = l >> 4;
        const int bi = (b >> 4) * 16;
        const int bj = (b & 15) * 16;

        f32x4 ac = {0.f,0.f,0.f,0.f}, ag = {0.f,0.f,0.f,0.f}, ah = {0.f,0.f,0.f,0.f};

        // c = x1 . x2^T  (16 ksteps, 4 per wave)
        const float* ar = x1 + (bi + lr) * DIN + kg * 8;
        const float* br = x2 + (bj + lr) * DIN + kg * 8;
        #pragma unroll
        for (int t = 0; t < 4; ++t) {
            const int k = (w + t * 4) * 32;
            bf16x8 a  = cvt8(*(const f32x4*)(ar + k), *(const f32x4*)(ar + k + 4));
            bf16x8 bv = cvt8(*(const f32x4*)(br + k), *(const f32x4*)(br + k + 4));
            ac = __builtin_amdgcn_mfma_f32_16x16x32_bf16(a, bv, ac, 0, 0, 0);
        }
        // g = g1 . g2^T, h = h1 . h2^T  (32 ksteps, 8 per wave)
        const short* ga = Gb + (bi + lr) * DHID + kg * 8;
        const short* gb = Gb + (NS + bj + lr) * DHID + kg * 8;
        const short* ha = Hb + (bi + lr) * DHID + kg * 8;
        const short* hb = Hb + (NS + bj + lr) * DHID + kg * 8;
        #pragma unroll
        for (int t = 0; t < 8; ++t) {
            const int k = (w + t * 4) * 32;
            bf16x8 a  = *(const bf16x8*)(ga + k);
            bf16x8 bv = *(const bf16x8*)(gb + k);
            ag = __builtin_amdgcn_mfma_f32_16x16x32_bf16(a, bv, ag, 0, 0, 0);
            bf16x8 a2 = *(const bf16x8*)(ha + k);
            bf16x8 b2 = *(const bf16x8*)(hb + k);
            ah = __builtin_amdgcn_mfma_f32_16x16x32_bf16(a2, b2, ah, 0, 0, 0);
        }

        __syncthreads();                 // smem reuse: phase-1 reads done (grid.sync passed)
        red2[0][w][l] = ac; red2[1][w][l] = ag; red2[2][w][l] = ah;
        __syncthreads();
        if (w == 0) {
            f32x4 c = red2[0][0][l], g = red2[1][0][l], h = red2[2][0][l];
            #pragma unroll
            for (int q = 1; q < 4; ++q) { c += red2[0][q][l]; g += red2[1][q][l]; h += red2[2][q][l]; }
            #pragma unroll
            for (int r = 0; r < 4; ++r)
                out[(bi + kg * 4 + r) * NS + (bj + lr)] = (c[r] + 1.f) * g[r] + h[r] + 1.f;
        }
    }
}

extern "C" void kernel_launch(void* const* d_in, const int* in_sizes, int n_in,
                              void* d_out, int out_size, void* d_ws, size_t ws_size,
                              hipStream_t stream) {
    const float* x1 = (const float*)d_in[0];   // [256,512]
    const float* x2 = (const float*)d_in[1];   // [256,512]
    const float* W1 = (const float*)d_in[2];   // [512,1024]
    const float* b1 = (const float*)d_in[3];   // [1024]
    const float* w2 = (const float*)d_in[4];   // [1024,1]
    // d_in[5] = b2: d f / d b2 == 1 always -> the "+1" term.

    short* Hb  = (short*)d_ws;                 // [512,1024] bf16, 1 MiB
    short* Gb  = Hb + 2 * NS * DHID;           // [512,1024] bf16, 1 MiB
    float* out = (float*)d_out;                // [256,256]

    void* args[] = { (void*)&x1, (void*)&x2, (void*)&W1, (void*)&b1,
                     (void*)&w2, (void*)&Hb, (void*)&Gb, (void*)&out };
    (void)hipLaunchCooperativeKernel((const void*)ntk_coop, dim3(256), dim3(256),
                                     args, 0, stream);
}

// Round 7
// 19.687 us; speedup vs baseline: 2.9056x; 2.9056x over previous
//
#include <hip/hip_runtime.h>
#include <hip/hip_bf16.h>

#define NS   256
#define DIN  512
#define DHID 1024

typedef __attribute__((ext_vector_type(8)))  short bf16x8;
typedef __attribute__((ext_vector_type(4)))  float f32x4;
typedef __attribute__((ext_vector_type(16))) float f32x16;

static __device__ __forceinline__ short f2bf(float f) {
    return __builtin_bit_cast(short, __float2bfloat16(f));   // RNE
}

static __device__ __forceinline__ bf16x8 cvt8(f32x4 a, f32x4 b) {
    bf16x8 r;
    r[0] = f2bf(a[0]); r[1] = f2bf(a[1]); r[2] = f2bf(a[2]); r[3] = f2bf(a[3]);
    r[4] = f2bf(b[0]); r[5] = f2bf(b[1]); r[6] = f2bf(b[2]); r[7] = f2bf(b[3]);
    return r;
}

// ---------------- K1: feature pass. 512 blocks x 256 thr (2 blocks/CU) ----------------
// Z = [x1;x2] @ W1 + b1; Hb = relu(Z), Gb = (Z>0)*w2 (bf16, ws).
// Block = 32 rows x 32 cols; 4 waves = 4-way K-split (8 ksteps of 32x32x16 each);
// LDS reduce (padded [4][64][17] floats -> stride 17, worst 2-way = free);
// epilogue split across all 4 waves (wave w writes D-regs 4w..4w+3).
// Frag layouts (m74/m101): A/B lane l -> row/col = l&31, k = (l>>5)*8 + i.
// D lane l, reg r -> col = l&31, row = (r&3) + 8*(r>>2) + 4*(l>>5).
__global__ __launch_bounds__(256) void ntk_feat(
    const float* __restrict__ x1, const float* __restrict__ x2,
    const float* __restrict__ W1, const float* __restrict__ b1,
    const float* __restrict__ w2,
    short* __restrict__ Hb, short* __restrict__ Gb)
{
    const int tid = threadIdx.x;
    const int l   = tid & 63;
    const int w   = tid >> 6;        // k-split index 0..3
    const int lc  = l & 31;          // A-row / B-col / D-col
    const int hk  = l >> 5;          // k half-group
    const int b   = blockIdx.x;

    const int r0 = (b >> 5) * 32;                    // row tile 0..480
    const int n0 = (b & 31) * 32;                    // col tile 0..992
    const int col = n0 + lc;

    const float* X  = (r0 < NS) ? (x1 + (size_t)r0 * DIN)
                                : (x2 + (size_t)(r0 - NS) * DIN);
    const float* ap = X + lc * DIN + w * 128 + hk * 8;
    const float* bp = W1 + (size_t)(w * 128 + hk * 8) * DHID + col;

    f32x16 acc = {};
    #pragma unroll
    for (int t = 0; t < 8; ++t) {                    // this wave's 8 ksteps
        const int k0 = t * 16;
        bf16x8 a = cvt8(*(const f32x4*)(ap + k0), *(const f32x4*)(ap + k0 + 4));
        f32x4 b0v, b1v;
        #pragma unroll
        for (int i = 0; i < 4; ++i) b0v[i] = bp[(size_t)(k0 + i) * DHID];
        #pragma unroll
        for (int i = 0; i < 4; ++i) b1v[i] = bp[(size_t)(k0 + 4 + i) * DHID];
        acc = __builtin_amdgcn_mfma_f32_32x32x16_bf16(a, cvt8(b0v, b1v), acc, 0, 0, 0);
    }

    __shared__ float red[4][64][17];                 // pad 17: stride coprime w/ 32 banks
    #pragma unroll
    for (int r = 0; r < 16; ++r) red[w][l][r] = acc[r];
    __syncthreads();

    // epilogue: wave w handles D-regs 4w..4w+3 (rows depend on reg + hk)
    const float bbv = b1[col], wwv = w2[col];
    #pragma unroll
    for (int r = 0; r < 4; ++r) {
        const int rr = w * 4 + r;                    // 0..15
        float s = red[0][l][rr] + red[1][l][rr] + red[2][l][rr] + red[3][l][rr];
        const int row = r0 + (rr & 3) + 8 * (rr >> 2) + 4 * hk;
        float z = s + bbv;
        Hb[row * DHID + col] = f2bf(z > 0.f ? z   : 0.f);
        Gb[row * DHID + col] = f2bf(z > 0.f ? wwv : 0.f);
    }
}

// ---------------- K2: all grams + combine. 256 blocks x 512 thr ----------------
// out[i,j] = (x1_i.x2_j + 1)*(g1_i.g2_j) + h1_i.h2_j + 1
// Block = one 16x16 tile; 8 waves split ksteps: c 16 -> 2/wave, g 32 -> 4/wave,
// h 32 -> 4/wave (10 MFMA_16x16x32 per wave). LDS reduce, wave 0 combines.
// Frag layouts (m89/m97): A/B lane l -> row/col = l&15, k = (l>>4)*8 + i.
// D lane l, reg r -> col = l&15, row = (l>>4)*4 + r.
__global__ __launch_bounds__(512) void ntk_gram(
    const float* __restrict__ x1, const float* __restrict__ x2,
    const short* __restrict__ Hb, const short* __restrict__ Gb,
    float* __restrict__ out)
{
    const int tid = threadIdx.x;
    const int l   = tid & 63;
    const int w   = tid >> 6;          // 0..7
    const int lr  = l & 15;
    const int kg  = l >> 4;
    const int bi  = (blockIdx.x >> 4) * 16;
    const int bj  = (blockIdx.x & 15) * 16;

    __shared__ f32x4 red[3][8][64];    // 24 KiB

    f32x4 ac = {0.f,0.f,0.f,0.f}, ag = {0.f,0.f,0.f,0.f}, ah = {0.f,0.f,0.f,0.f};

    // c = x1 . x2^T : 16 ksteps, 2 per wave (ksteps 2w, 2w+1)
    const float* ar = x1 + (bi + lr) * DIN + kg * 8;
    const float* br = x2 + (bj + lr) * DIN + kg * 8;
    #pragma unroll
    for (int t = 0; t < 2; ++t) {
        const int k = (w * 2 + t) * 32;
        bf16x8 a  = cvt8(*(const f32x4*)(ar + k), *(const f32x4*)(ar + k + 4));
        bf16x8 bv = cvt8(*(const f32x4*)(br + k), *(const f32x4*)(br + k + 4));
        ac = __builtin_amdgcn_mfma_f32_16x16x32_bf16(a, bv, ac, 0, 0, 0);
    }
    // g,h : 32 ksteps each, 4 per wave (ksteps 4w..4w+3)
    const short* ga = Gb + (bi + lr) * DHID + kg * 8;
    const short* gb = Gb + (NS + bj + lr) * DHID + kg * 8;
    const short* ha = Hb + (bi + lr) * DHID + kg * 8;
    const short* hb = Hb + (NS + bj + lr) * DHID + kg * 8;
    #pragma unroll
    for (int t = 0; t < 4; ++t) {
        const int k = (w * 4 + t) * 32;
        bf16x8 a  = *(const bf16x8*)(ga + k);
        bf16x8 bv = *(const bf16x8*)(gb + k);
        ag = __builtin_amdgcn_mfma_f32_16x16x32_bf16(a, bv, ag, 0, 0, 0);
        bf16x8 a2 = *(const bf16x8*)(ha + k);
        bf16x8 b2 = *(const bf16x8*)(hb + k);
        ah = __builtin_amdgcn_mfma_f32_16x16x32_bf16(a2, b2, ah, 0, 0, 0);
    }

    red[0][w][l] = ac; red[1][w][l] = ag; red[2][w][l] = ah;
    __syncthreads();
    if (w == 0) {
        f32x4 c = red[0][0][l], g = red[1][0][l], h = red[2][0][l];
        #pragma unroll
        for (int q = 1; q < 8; ++q) { c += red[0][q][l]; g += red[1][q][l]; h += red[2][q][l]; }
        #pragma unroll
        for (int r = 0; r < 4; ++r)
            out[(bi + kg * 4 + r) * NS + (bj + lr)] = (c[r] + 1.f) * g[r] + h[r] + 1.f;
    }
}

extern "C" void kernel_launch(void* const* d_in, const int* in_sizes, int n_in,
                              void* d_out, int out_size, void* d_ws, size_t ws_size,
                              hipStream_t stream) {
    const float* x1 = (const float*)d_in[0];   // [256,512]
    const float* x2 = (const float*)d_in[1];   // [256,512]
    const float* W1 = (const float*)d_in[2];   // [512,1024]
    const float* b1 = (const float*)d_in[3];   // [1024]
    const float* w2 = (const float*)d_in[4];   // [1024,1]
    // d_in[5] = b2: d f / d b2 == 1 always -> the "+1" term.

    short* Hb  = (short*)d_ws;                 // [512,1024] bf16, 1 MiB
    short* Gb  = Hb + 2 * NS * DHID;           // [512,1024] bf16, 1 MiB
    float* out = (float*)d_out;                // [256,256]

    ntk_feat<<<512, 256, 0, stream>>>(x1, x2, W1, b1, w2, Hb, Gb);
    ntk_gram<<<256, 512, 0, stream>>>(x1, x2, Hb, Gb, out);
}